// Round 8
// baseline (220.154 us; speedup 1.0000x reference)
//
#include <hip/hip_runtime.h>
#include <cstddef>

#define F 128    // F_IN == UNITS == 128
#define LDB 136  // LDS row stride in bf16 units: 128 + 8 pad

typedef __attribute__((ext_vector_type(8))) short bf16x8;
typedef __attribute__((ext_vector_type(4))) float f32x4;

__device__ __forceinline__ unsigned short f2bf(float f) {
  unsigned int u = __float_as_uint(f);
  u += 0x7fffu + ((u >> 16) & 1u);  // round-to-nearest-even
  return (unsigned short)(u >> 16);
}

// ---------------------------------------------------------------------------
// Kernel 0: merged setup. Blocks [0, nbA) build row_ptr[N+1] from SORTED
// erow (edge-parallel); blocks [nbA, nbA+64) transpose+convert W -> Wt bf16.
// ---------------------------------------------------------------------------
__global__ __launch_bounds__(256) void setup(const int* __restrict__ erow,
                                             int n_edges, int n_nodes, int nbA,
                                             int* __restrict__ row_ptr,
                                             const float* __restrict__ W,
                                             unsigned short* __restrict__ Wt) {
  const int bid = blockIdx.x;
  if (bid < nbA) {
    const int e = bid * 256 + threadIdx.x;
    if (e > n_edges) return;
    int r_lo, r_hi, val;
    if (e == 0) {
      r_lo = 0; r_hi = erow[0]; val = 0;
    } else if (e == n_edges) {
      r_lo = erow[n_edges - 1] + 1; r_hi = n_nodes; val = n_edges;
    } else {
      const int rp = erow[e - 1], rc = erow[e];
      r_lo = rp + 1; r_hi = rc; val = e;
    }
    for (int r = r_lo; r <= r_hi; ++r) row_ptr[r] = val;
  } else {
    const int idx = (bid - nbA) * 256 + threadIdx.x;  // 0..16383
    const int k = idx >> 7, n = idx & 127;
    Wt[n * F + k] = f2bf(W[idx]);
  }
}

// ---------------------------------------------------------------------------
// Kernel 1: H_bf16 = bf16( X @ W )  via MFMA 16x16x32 bf16 (frozen since r5).
// NOTE: launched TWICE this round as a duration diagnostic (idempotent).
// ---------------------------------------------------------------------------
__global__ __launch_bounds__(256) void gemm_mfma(const float* __restrict__ X,
                                                 const unsigned short* __restrict__ Wt,
                                                 unsigned short* __restrict__ H,
                                                 int n_nodes) {
  __shared__ alignas(16) unsigned short Bs[128 * LDB];  // 34.8 KB
  const int tid = threadIdx.x;

  {  // stage Wt (bf16, k-contiguous): 2048 16B chunks, coalesced
    const uint4* src = (const uint4*)Wt;
    #pragma unroll
    for (int i = 0; i < 8; ++i) {
      const int idx = tid + i * 256;
      const int n = idx >> 4, c8 = idx & 15;
      *(uint4*)&Bs[n * LDB + c8 * 8] = src[idx];
    }
  }
  __syncthreads();

  const int wave = tid >> 6;
  const int lane = tid & 63;
  const int l15 = lane & 15;
  const int quad = lane >> 4;
  const int rbase = blockIdx.x * 128 + wave * 32;

  const float* xr[2];
  #pragma unroll
  for (int rt = 0; rt < 2; ++rt) {
    int r = rbase + rt * 16 + l15;
    if (r > n_nodes - 1) r = n_nodes - 1;
    xr[rt] = X + (size_t)r * F;
  }

  f32x4 acc[2][8] = {};

  #pragma unroll
  for (int ks = 0; ks < 4; ++ks) {
    const int k0 = ks * 32 + quad * 8;
    bf16x8 a[2], b[8];
    #pragma unroll
    for (int rt = 0; rt < 2; ++rt) {
      const float4 x0 = *(const float4*)(xr[rt] + k0);
      const float4 x1 = *(const float4*)(xr[rt] + k0 + 4);
      bf16x8 t;
      t[0] = (short)f2bf(x0.x); t[1] = (short)f2bf(x0.y);
      t[2] = (short)f2bf(x0.z); t[3] = (short)f2bf(x0.w);
      t[4] = (short)f2bf(x1.x); t[5] = (short)f2bf(x1.y);
      t[6] = (short)f2bf(x1.z); t[7] = (short)f2bf(x1.w);
      a[rt] = t;
    }
    #pragma unroll
    for (int ct = 0; ct < 8; ++ct)
      b[ct] = *(const bf16x8*)&Bs[(ct * 16 + l15) * LDB + k0];
    #pragma unroll
    for (int rt = 0; rt < 2; ++rt)
      #pragma unroll
      for (int ct = 0; ct < 8; ++ct)
        acc[rt][ct] = __builtin_amdgcn_mfma_f32_16x16x32_bf16(
            b[ct], a[rt], acc[rt][ct], 0, 0, 0);  // swapped -> transposed D
  }

  #pragma unroll
  for (int rt = 0; rt < 2; ++rt) {
    const int row = rbase + rt * 16 + l15;
    if (row < n_nodes) {
      #pragma unroll
      for (int ct = 0; ct < 8; ++ct) {
        const unsigned int d0 = (unsigned int)f2bf(acc[rt][ct][0]) |
                                ((unsigned int)f2bf(acc[rt][ct][1]) << 16);
        const unsigned int d1 = (unsigned int)f2bf(acc[rt][ct][2]) |
                                ((unsigned int)f2bf(acc[rt][ct][3]) << 16);
        uint2 u; u.x = d0; u.y = d1;
        *(uint2*)&H[(size_t)row * F + ct * 16 + quad * 4] = u;
      }
    }
  }
}

// ---------------------------------------------------------------------------
// Kernel 2: out[n,:] = sigmoid( sum_e val[e]*H[col[e],:] + bias ), H bf16.
// Round 8: 2 nodes per wave, 32 lanes per node, lane covers 4 features via
// one 8B (uint2) load. Padding waste E[max2 Poisson16]/16 ~ 1.14x (was 1.33x
// with 4 nodes/wave); VGPR ~28 -> near-100% occupancy.
// ---------------------------------------------------------------------------
__global__ __launch_bounds__(256) void spmm_bias_sigmoid(
    const int* __restrict__ row_ptr, const int* __restrict__ ecol,
    const float* __restrict__ eval, const unsigned short* __restrict__ H,
    const float* __restrict__ bias, float* __restrict__ out, int n_nodes) {
  const int wave = threadIdx.x >> 6;
  const int lane = threadIdx.x & 63;
  const int g = lane >> 5;    // node slot within wave (0/1)
  const int fl = lane & 31;   // feature-lane: features fl*4 .. fl*4+3
  const int node = blockIdx.x * 8 + wave * 2 + g;
  const bool valid = (node < n_nodes);

  const int lo = valid ? row_ptr[node] : 0;
  const int hi = valid ? row_ptr[node + 1] : 0;
  const int deg = hi - lo;

  // wave-wide max of the 2 group degrees
  int dmax = max(deg, __shfl_xor(deg, 32, 64));

  const char* Hb = (const char*)H + fl * 8;

  float acc[4] = {};

  for (int base = 0; base < dmax; base += 32) {
    // chunk edge data: lane l31 of group g holds edge lo+base+l31
    int voff = 0;
    float vv = 0.f;
    if (base + fl < deg) {
      const int e = lo + base + fl;
      voff = ecol[e] << 8;  // byte offset of H row (c * 256B)
      vv = eval[e];
    }
    const int cnt = min(dmax - base, 32);
    #pragma unroll 8
    for (int j = 0; j < cnt; ++j) {
      const int idx = ((lane & 32) + j) << 2;  // own group's lane j
      const int ro = __builtin_amdgcn_ds_bpermute(idx, voff);
      const float v = __int_as_float(
          __builtin_amdgcn_ds_bpermute(idx, __float_as_int(vv)));
      // padded lanes: ro=0, v=0 -> harmless hot H[0,:] load, zero contrib
      const uint2 h = *(const uint2*)(Hb + ro);
      acc[0] += v * __uint_as_float(h.x << 16);
      acc[1] += v * __uint_as_float(h.x & 0xffff0000u);
      acc[2] += v * __uint_as_float(h.y << 16);
      acc[3] += v * __uint_as_float(h.y & 0xffff0000u);
    }
  }

  if (valid) {
    const float4 b = *(const float4*)&bias[fl * 4];
    float4 o;
    o.x = 1.f / (1.f + expf(-(acc[0] + b.x)));
    o.y = 1.f / (1.f + expf(-(acc[1] + b.y)));
    o.z = 1.f / (1.f + expf(-(acc[2] + b.z)));
    o.w = 1.f / (1.f + expf(-(acc[3] + b.w)));
    *(float4*)&out[(size_t)node * F + fl * 4] = o;  // 512B/node contiguous
  }
}

// ---------------------------------------------------------------------------
extern "C" void kernel_launch(void* const* d_in, const int* in_sizes, int n_in,
                              void* d_out, int out_size, void* d_ws, size_t ws_size,
                              hipStream_t stream) {
  const float* X    = (const float*)d_in[0];
  const int*   erow = (const int*)  d_in[1];
  const int*   ecol = (const int*)  d_in[2];
  const float* eval = (const float*)d_in[3];
  const float* W    = (const float*)d_in[4];
  const float* bias = (const float*)d_in[5];
  float* out = (float*)d_out;

  const int n_nodes = in_sizes[0] / F;  // 100000
  const int n_edges = in_sizes[1];      // 1600000

  // Workspace layout (16B aligned):
  //   H  : n_nodes*F bf16   = 25,600,000 B
  //   rp : (n_nodes+1) int  =    400,004 B (padded to 16)
  //   Wt : F*F bf16         =     32,768 B
  char* ws = (char*)d_ws;
  unsigned short* H = (unsigned short*)ws;
  size_t off = (size_t)n_nodes * F * sizeof(unsigned short);
  int* row_ptr = (int*)(ws + off);
  off += ((size_t)(n_nodes + 1) * sizeof(int) + 15) & ~(size_t)15;
  unsigned short* Wt = (unsigned short*)(ws + off);

  const int nbA = (n_edges + 256) / 256;
  const int nbB = (F * F) / 256;  // 64
  setup<<<nbA + nbB, 256, 0, stream>>>(erow, n_edges, n_nodes, nbA, row_ptr,
                                       W, Wt);
  // DIAGNOSTIC (this round only): gemm launched twice — idempotent, same
  // work every call. Total delta vs r7 identity isolates gemm's duration:
  // g = T8 - p8 - 121.8us. Revert to single launch next round.
  gemm_mfma<<<(n_nodes + 127) / 128, 256, 0, stream>>>(X, Wt, H, n_nodes);
  gemm_mfma<<<(n_nodes + 127) / 128, 256, 0, stream>>>(X, Wt, H, n_nodes);
  spmm_bias_sigmoid<<<(n_nodes + 7) / 8, 256, 0, stream>>>(
      row_ptr, ecol, eval, H, bias, out, n_nodes);
}

// Round 9
// 189.905 us; speedup vs baseline: 1.1593x; 1.1593x over previous
//
#include <hip/hip_runtime.h>
#include <cstddef>

#define F 128    // F_IN == UNITS == 128
#define LDB 136  // LDS row stride in bf16 units: 128 + 8 pad

typedef __attribute__((ext_vector_type(8))) short bf16x8;
typedef __attribute__((ext_vector_type(4))) float f32x4;

__device__ __forceinline__ unsigned short f2bf(float f) {
  unsigned int u = __float_as_uint(f);
  u += 0x7fffu + ((u >> 16) & 1u);  // round-to-nearest-even
  return (unsigned short)(u >> 16);
}

// ---------------------------------------------------------------------------
// Kernel 0: merged setup. Blocks [0, nbA) build row_ptr[N+1] from SORTED
// erow (edge-parallel); blocks [nbA, nbA+64) transpose+convert W -> Wt bf16.
// (~5 us measured-by-elimination; near floor.)
// ---------------------------------------------------------------------------
__global__ __launch_bounds__(256) void setup(const int* __restrict__ erow,
                                             int n_edges, int n_nodes, int nbA,
                                             int* __restrict__ row_ptr,
                                             const float* __restrict__ W,
                                             unsigned short* __restrict__ Wt) {
  const int bid = blockIdx.x;
  if (bid < nbA) {
    const int e = bid * 256 + threadIdx.x;
    if (e > n_edges) return;
    int r_lo, r_hi, val;
    if (e == 0) {
      r_lo = 0; r_hi = erow[0]; val = 0;
    } else if (e == n_edges) {
      r_lo = erow[n_edges - 1] + 1; r_hi = n_nodes; val = n_edges;
    } else {
      const int rp = erow[e - 1], rc = erow[e];
      r_lo = rp + 1; r_hi = rc; val = e;
    }
    for (int r = r_lo; r <= r_hi; ++r) row_ptr[r] = val;
  } else {
    const int idx = (bid - nbA) * 256 + threadIdx.x;  // 0..16383
    const int k = idx >> 7, n = idx & 127;
    Wt[n * F + k] = f2bf(W[idx]);
  }
}

// ---------------------------------------------------------------------------
// Kernel 1: H_bf16 = bf16( X @ W )  via MFMA 16x16x32 bf16.
// 18.0 us measured (r8 double-launch diagnostic) vs ~13 us memory floor.
// Swapped-operand mfma -> D transposed: lane (quad,l15) holds node row
// rt*16+l15, features ct*16+quad*4+{0..3} -> one 8B store per (rt,ct).
// ---------------------------------------------------------------------------
__global__ __launch_bounds__(256) void gemm_mfma(const float* __restrict__ X,
                                                 const unsigned short* __restrict__ Wt,
                                                 unsigned short* __restrict__ H,
                                                 int n_nodes) {
  __shared__ alignas(16) unsigned short Bs[128 * LDB];  // 34.8 KB
  const int tid = threadIdx.x;

  {  // stage Wt (bf16, k-contiguous): 2048 16B chunks, coalesced
    const uint4* src = (const uint4*)Wt;
    #pragma unroll
    for (int i = 0; i < 8; ++i) {
      const int idx = tid + i * 256;
      const int n = idx >> 4, c8 = idx & 15;
      *(uint4*)&Bs[n * LDB + c8 * 8] = src[idx];
    }
  }
  __syncthreads();

  const int wave = tid >> 6;
  const int lane = tid & 63;
  const int l15 = lane & 15;
  const int quad = lane >> 4;
  const int rbase = blockIdx.x * 128 + wave * 32;

  const float* xr[2];
  #pragma unroll
  for (int rt = 0; rt < 2; ++rt) {
    int r = rbase + rt * 16 + l15;
    if (r > n_nodes - 1) r = n_nodes - 1;
    xr[rt] = X + (size_t)r * F;
  }

  f32x4 acc[2][8] = {};

  #pragma unroll
  for (int ks = 0; ks < 4; ++ks) {
    const int k0 = ks * 32 + quad * 8;
    bf16x8 a[2], b[8];
    #pragma unroll
    for (int rt = 0; rt < 2; ++rt) {
      const float4 x0 = *(const float4*)(xr[rt] + k0);
      const float4 x1 = *(const float4*)(xr[rt] + k0 + 4);
      bf16x8 t;
      t[0] = (short)f2bf(x0.x); t[1] = (short)f2bf(x0.y);
      t[2] = (short)f2bf(x0.z); t[3] = (short)f2bf(x0.w);
      t[4] = (short)f2bf(x1.x); t[5] = (short)f2bf(x1.y);
      t[6] = (short)f2bf(x1.z); t[7] = (short)f2bf(x1.w);
      a[rt] = t;
    }
    #pragma unroll
    for (int ct = 0; ct < 8; ++ct)
      b[ct] = *(const bf16x8*)&Bs[(ct * 16 + l15) * LDB + k0];
    #pragma unroll
    for (int rt = 0; rt < 2; ++rt)
      #pragma unroll
      for (int ct = 0; ct < 8; ++ct)
        acc[rt][ct] = __builtin_amdgcn_mfma_f32_16x16x32_bf16(
            b[ct], a[rt], acc[rt][ct], 0, 0, 0);  // swapped -> transposed D
  }

  #pragma unroll
  for (int rt = 0; rt < 2; ++rt) {
    const int row = rbase + rt * 16 + l15;
    if (row < n_nodes) {
      #pragma unroll
      for (int ct = 0; ct < 8; ++ct) {
        const unsigned int d0 = (unsigned int)f2bf(acc[rt][ct][0]) |
                                ((unsigned int)f2bf(acc[rt][ct][1]) << 16);
        const unsigned int d1 = (unsigned int)f2bf(acc[rt][ct][2]) |
                                ((unsigned int)f2bf(acc[rt][ct][3]) << 16);
        uint2 u; u.x = d0; u.y = d1;
        *(uint2*)&H[(size_t)row * F + ct * 16 + quad * 4] = u;
      }
    }
  }
}

// ---------------------------------------------------------------------------
// Kernel 2: out[n,:] = sigmoid( sum_e val[e]*H[col[e],:] + bias ), H bf16.
// BEST MEASURED CONFIG (r6, 69.0 us): 4 nodes/wave, 16 lanes/node, one
// dwordx4 (16B) per lane per edge, cnt==16 chunk fully unrolled (16 gathers
// in flight). Plateau evidence: 4/8/16-deep MLP x 32-100% occ x 8/16B lanes
// all land 69-80 us at FETCH ~= per-XCD compulsory H refill (8 x 22.5 MB) —
// L3-gather-service bound; columns uniform-random, no locality to mine.
// ---------------------------------------------------------------------------
__global__ __launch_bounds__(256) void spmm_bias_sigmoid(
    const int* __restrict__ row_ptr, const int* __restrict__ ecol,
    const float* __restrict__ eval, const unsigned short* __restrict__ H,
    const float* __restrict__ bias, float* __restrict__ out, int n_nodes) {
  const int wave = threadIdx.x >> 6;
  const int lane = threadIdx.x & 63;
  const int g = lane >> 4;   // node slot within wave
  const int fl = lane & 15;  // feature-lane: features fl*8 .. fl*8+7
  const int node = blockIdx.x * 16 + wave * 4 + g;
  const bool valid = (node < n_nodes);

  const int lo = valid ? row_ptr[node] : 0;
  const int hi = valid ? row_ptr[node + 1] : 0;
  const int deg = hi - lo;

  int dmax = deg;
  dmax = max(dmax, __shfl_xor(dmax, 16, 64));
  dmax = max(dmax, __shfl_xor(dmax, 32, 64));

  const int bpbase = (lane & 48) * 4;  // byte idx of own group's lane 0
  const char* Hb = (const char*)H + fl * 16;

  float acc[8] = {};

#define SPMM_STEP(j)                                                        \
  {                                                                         \
    const int idx = bpbase + (j) * 4;                                       \
    const int ro = __builtin_amdgcn_ds_bpermute(idx, voff);                 \
    const float v = __int_as_float(                                         \
        __builtin_amdgcn_ds_bpermute(idx, __float_as_int(vv)));             \
    const uint4 h = *(const uint4*)(Hb + ro);                               \
    acc[0] += v * __uint_as_float(h.x << 16);                               \
    acc[1] += v * __uint_as_float(h.x & 0xffff0000u);                       \
    acc[2] += v * __uint_as_float(h.y << 16);                               \
    acc[3] += v * __uint_as_float(h.y & 0xffff0000u);                       \
    acc[4] += v * __uint_as_float(h.z << 16);                               \
    acc[5] += v * __uint_as_float(h.z & 0xffff0000u);                       \
    acc[6] += v * __uint_as_float(h.w << 16);                               \
    acc[7] += v * __uint_as_float(h.w & 0xffff0000u);                       \
  }

  for (int base = 0; base < dmax; base += 16) {
    int voff = 0;
    float vv = 0.f;
    if (base + fl < deg) {
      const int e = lo + base + fl;
      voff = ecol[e] << 8;  // byte offset of H row (c * 256B)
      vv = eval[e];
    }
    const int cnt = min(dmax - base, 16);
    if (cnt == 16) {
      #pragma unroll
      for (int j = 0; j < 16; ++j) SPMM_STEP(j)
    } else {
      #pragma unroll 4
      for (int j = 0; j < cnt; ++j) SPMM_STEP(j)
    }
  }
#undef SPMM_STEP

  if (valid) {
    const float4 b0 = *(const float4*)&bias[fl * 8];
    const float4 b1 = *(const float4*)&bias[fl * 8 + 4];
    float4 o0, o1;
    o0.x = 1.f / (1.f + expf(-(acc[0] + b0.x)));
    o0.y = 1.f / (1.f + expf(-(acc[1] + b0.y)));
    o0.z = 1.f / (1.f + expf(-(acc[2] + b0.z)));
    o0.w = 1.f / (1.f + expf(-(acc[3] + b0.w)));
    o1.x = 1.f / (1.f + expf(-(acc[4] + b1.x)));
    o1.y = 1.f / (1.f + expf(-(acc[5] + b1.y)));
    o1.z = 1.f / (1.f + expf(-(acc[6] + b1.z)));
    o1.w = 1.f / (1.f + expf(-(acc[7] + b1.w)));
    float* op = out + (size_t)node * F + fl * 8;
    *(float4*)op = o0;
    *(float4*)(op + 4) = o1;
  }
}

// ---------------------------------------------------------------------------
extern "C" void kernel_launch(void* const* d_in, const int* in_sizes, int n_in,
                              void* d_out, int out_size, void* d_ws, size_t ws_size,
                              hipStream_t stream) {
  const float* X    = (const float*)d_in[0];
  const int*   erow = (const int*)  d_in[1];
  const int*   ecol = (const int*)  d_in[2];
  const float* eval = (const float*)d_in[3];
  const float* W    = (const float*)d_in[4];
  const float* bias = (const float*)d_in[5];
  float* out = (float*)d_out;

  const int n_nodes = in_sizes[0] / F;  // 100000
  const int n_edges = in_sizes[1];      // 1600000

  // Workspace layout (16B aligned):
  //   H  : n_nodes*F bf16   = 25,600,000 B
  //   rp : (n_nodes+1) int  =    400,004 B (padded to 16)
  //   Wt : F*F bf16         =     32,768 B
  char* ws = (char*)d_ws;
  unsigned short* H = (unsigned short*)ws;
  size_t off = (size_t)n_nodes * F * sizeof(unsigned short);
  int* row_ptr = (int*)(ws + off);
  off += ((size_t)(n_nodes + 1) * sizeof(int) + 15) & ~(size_t)15;
  unsigned short* Wt = (unsigned short*)(ws + off);

  const int nbA = (n_edges + 256) / 256;
  const int nbB = (F * F) / 256;  // 64
  setup<<<nbA + nbB, 256, 0, stream>>>(erow, n_edges, n_nodes, nbA, row_ptr,
                                       W, Wt);
  gemm_mfma<<<(n_nodes + 127) / 128, 256, 0, stream>>>(X, Wt, H, n_nodes);
  spmm_bias_sigmoid<<<(n_nodes + 15) / 16, 256, 0, stream>>>(
      row_ptr, ecol, eval, H, bias, out, n_nodes);
}